// Round 1
// baseline (115.212 us; speedup 1.0000x reference)
//
#include <hip/hip_runtime.h>

#define NROWS 8192
#define EDIM  256
#define NB    64          // 8192 / 128 row-blocks
#define XN_OFF 256        // ws byte offset of bf16 xn array (cnt[4] lives at 0)

typedef __bf16 bf16x8 __attribute__((ext_vector_type(8)));
typedef float  f32x4  __attribute__((ext_vector_type(4)));

__device__ __forceinline__ unsigned short f2bf(float f) {
  unsigned int u = __float_as_uint(f);
  u += 0x7fffu + ((u >> 16) & 1u);      // round-to-nearest-even
  return (unsigned short)(u >> 16);
}

__device__ __forceinline__ void gl_lds16(const void* g, void* l) {
  __builtin_amdgcn_global_load_lds(
      (const __attribute__((address_space(1))) unsigned int*)g,
      (__attribute__((address_space(3))) unsigned int*)l, 16, 0, 0);
}

// ---- row normalize + bf16 convert: 1 wave per row, 4 rows per block ----
__global__ __launch_bounds__(256) void k_norm(const float* __restrict__ x,
                                              unsigned short* __restrict__ xn) {
  int row  = blockIdx.x * 4 + (threadIdx.x >> 6);
  int lane = threadIdx.x & 63;
  float4 v = reinterpret_cast<const float4*>(x)[row * 64 + lane];
  float ss = v.x * v.x + v.y * v.y + v.z * v.z + v.w * v.w;
#pragma unroll
  for (int off = 32; off; off >>= 1) ss += __shfl_xor(ss, off);
  float inv = 1.0f / fmaxf(sqrtf(ss), 1e-8f);
  ushort4 o;
  o.x = f2bf(v.x * inv); o.y = f2bf(v.y * inv);
  o.z = f2bf(v.z * inv); o.w = f2bf(v.w * inv);
  reinterpret_cast<ushort4*>(xn)[row * 64 + lane] = o;
}

// ---- class histogram ----
__global__ __launch_bounds__(256) void k_hist(const int* __restrict__ t,
                                              int* __restrict__ cnt) {
  __shared__ int lc[4];
  if (threadIdx.x < 4) lc[threadIdx.x] = 0;
  __syncthreads();
  int i = blockIdx.x * 256 + threadIdx.x;
  atomicAdd(&lc[t[i]], 1);
  __syncthreads();
  if (threadIdx.x < 4) atomicAdd(&cnt[threadIdx.x], lc[threadIdx.x]);
}

// ---- fused triangular GEMM-reduce: one 128x128 tile per block ----
__global__ __launch_bounds__(256) void k_main(const unsigned short* __restrict__ xn,
                                              const int* __restrict__ tgt,
                                              const int* __restrict__ cnt,
                                              float* __restrict__ out) {
  __shared__ short lsA[128 * 256];   // 64 KB
  __shared__ short lsB[128 * 256];   // 64 KB
  __shared__ int   ltrow[128], ltcol[128];
  __shared__ float lW[16];
  __shared__ int   lsL;
  __shared__ float wred[4];

  // block -> (r, cb) strict-upper-inclusive triangular pair
  int bid = blockIdx.x;
  int r = 0, rem = bid;
  while (rem >= NB - r) { rem -= NB - r; ++r; }
  int cb = r + rem;

  const int tid = threadIdx.x;
  const int wave = tid >> 6, lane = tid & 63;

  const char* xb   = (const char*)xn;
  const char* srcA = xb + (size_t)r  * 128 * 512;
  const char* srcB = xb + (size_t)cb * 128 * 512;
  char* lA = (char*)lsA;
  char* lB = (char*)lsB;

  // stage both 128x256 bf16 tiles; linear LDS dest + inverse-swizzled global src
  {
    int inner = (lane & 31) * 16;
#pragma unroll
    for (int it = 0; it < 16; ++it) {
      int rbase = it * 8 + wave * 2;          // wave-uniform
      int row   = rbase + (lane >> 5);
      int sw    = (row & 7) << 4;
      gl_lds16(srcA + (size_t)row * 512 + (inner ^ sw), lA + rbase * 512);
      gl_lds16(srcB + (size_t)row * 512 + (inner ^ sw), lB + rbase * 512);
    }
  }
  if (tid < 128) { ltrow[tid] = tgt[r * 128 + tid]; ltcol[tid] = tgt[cb * 128 + tid]; }
  if (tid < 16) {
    int ta = tid >> 2, tb = tid & 3;
    float w = 0.0f;
#pragma unroll
    for (int i = 0; i < 4; ++i) {
      int ci = cnt[i];
      if (ci > 0 && ((ta == i) == (tb == i))) w += 1.0f / (float)ci;
    }
    lW[tid] = w;
  }
  if (tid == 0) {
    int L = -1;
    for (int i = 0; i < 4; ++i) if (cnt[i] > 0) L = i;
    lsL = L;
  }
  __syncthreads();

  // 2x2 waves of 64x64; 4x4 frags of 16x16x32
  const int wr = (wave >> 1) * 64, wc = (wave & 1) * 64;
  f32x4 acc[4][4];
#pragma unroll
  for (int m = 0; m < 4; ++m)
#pragma unroll
    for (int n = 0; n < 4; ++n)
      acc[m][n] = (f32x4){0.f, 0.f, 0.f, 0.f};

  const int l15 = lane & 15;
  const int kb_lane = (lane >> 4) << 4;       // 0,16,32,48 byte k-offset
#pragma unroll
  for (int kk = 0; kk < 8; ++kk) {
    bf16x8 af[4], bfr[4];
    int kb = kk * 64 + kb_lane;
#pragma unroll
    for (int m = 0; m < 4; ++m) {
      int arow = wr + m * 16 + l15;
      af[m] = *reinterpret_cast<const bf16x8*>(lA + arow * 512 + (kb ^ ((arow & 7) << 4)));
    }
#pragma unroll
    for (int n = 0; n < 4; ++n) {
      int brow = wc + n * 16 + l15;
      bfr[n] = *reinterpret_cast<const bf16x8*>(lB + brow * 512 + (kb ^ ((brow & 7) << 4)));
    }
#pragma unroll
    for (int m = 0; m < 4; ++m)
#pragma unroll
      for (int n = 0; n < 4; ++n)
        acc[m][n] = __builtin_amdgcn_mfma_f32_16x16x32_bf16(af[m], bfr[n], acc[m][n], 0, 0, 0);
  }

  // epilogue: C/D layout col=lane&15, row=(lane>>4)*4+reg (m89-verified)
  const int L = lsL;
  float lsum = 0.0f;
  const int rowj = (lane >> 4) * 4;
#pragma unroll
  for (int m = 0; m < 4; ++m) {
#pragma unroll
    for (int n = 0; n < 4; ++n) {
#pragma unroll
      for (int j = 0; j < 4; ++j) {
        int ar = wr + m * 16 + rowj + j;
        int bc = wc + n * 16 + l15;
        int ga = r * 128 + ar, gb = cb * 128 + bc;
        if (ga < gb) {
          float cv = acc[m][n][j];
          int ta = ltrow[ar], tb = ltcol[bc];
          float contrib = lW[ta * 4 + tb] * (1.0f - cv);
          if ((ta == L) != (tb == L)) contrib += fmaxf(cv - 0.5f, 0.0f);
          lsum += contrib;
        }
      }
    }
  }
#pragma unroll
  for (int off = 32; off; off >>= 1) lsum += __shfl_xor(lsum, off);
  if (lane == 0) wred[wave] = lsum;
  __syncthreads();
  if (tid == 0) atomicAdd(out, (wred[0] + wred[1] + wred[2] + wred[3]) * (1.0f / 8192.0f));
}

extern "C" void kernel_launch(void* const* d_in, const int* in_sizes, int n_in,
                              void* d_out, int out_size, void* d_ws, size_t ws_size,
                              hipStream_t stream) {
  (void)in_sizes; (void)n_in; (void)out_size; (void)ws_size;
  const float* x  = (const float*)d_in[0];
  const int* tgt  = (const int*)d_in[1];
  float* out      = (float*)d_out;
  int* cnt        = (int*)d_ws;
  unsigned short* xn = (unsigned short*)((char*)d_ws + XN_OFF);

  hipMemsetAsync(d_out, 0, sizeof(float), stream);
  hipMemsetAsync(cnt, 0, 4 * sizeof(int), stream);
  k_norm<<<NROWS / 4, 256, 0, stream>>>(x, xn);
  k_hist<<<NROWS / 256, 256, 0, stream>>>(tgt, cnt);
  k_main<<<NB * (NB + 1) / 2, 256, 0, stream>>>(xn, tgt, cnt, out);
}

// Round 2
// 83.246 us; speedup vs baseline: 1.3840x; 1.3840x over previous
//
#include <hip/hip_runtime.h>

#define NROWS 8192
#define EDIM  256
#define NB    64          // 8192 / 128 row-blocks
#define XN_OFF 256        // ws byte offset of bf16 xn array (cnt[4] lives at 0)
#define BKB   128         // bytes per K-chunk row (64 bf16 elems)
#define NCHUNK 4          // 256 elems / 64

typedef __bf16 bf16x8 __attribute__((ext_vector_type(8)));
typedef float  f32x4  __attribute__((ext_vector_type(4)));

__device__ __forceinline__ unsigned short f2bf(float f) {
  unsigned int u = __float_as_uint(f);
  u += 0x7fffu + ((u >> 16) & 1u);      // round-to-nearest-even
  return (unsigned short)(u >> 16);
}

__device__ __forceinline__ void gl_lds16(const void* g, void* l) {
  __builtin_amdgcn_global_load_lds(
      (const __attribute__((address_space(1))) unsigned int*)g,
      (__attribute__((address_space(3))) unsigned int*)l, 16, 0, 0);
}

// ---- row normalize + bf16 convert: 1 wave per row, 4 rows per block ----
__global__ __launch_bounds__(256) void k_norm(const float* __restrict__ x,
                                              unsigned short* __restrict__ xn) {
  int row  = blockIdx.x * 4 + (threadIdx.x >> 6);
  int lane = threadIdx.x & 63;
  float4 v = reinterpret_cast<const float4*>(x)[row * 64 + lane];
  float ss = v.x * v.x + v.y * v.y + v.z * v.z + v.w * v.w;
#pragma unroll
  for (int off = 32; off; off >>= 1) ss += __shfl_xor(ss, off);
  float inv = 1.0f / fmaxf(sqrtf(ss), 1e-8f);
  ushort4 o;
  o.x = f2bf(v.x * inv); o.y = f2bf(v.y * inv);
  o.z = f2bf(v.z * inv); o.w = f2bf(v.w * inv);
  reinterpret_cast<ushort4*>(xn)[row * 64 + lane] = o;
}

// ---- class histogram ----
__global__ __launch_bounds__(256) void k_hist(const int* __restrict__ t,
                                              int* __restrict__ cnt) {
  __shared__ int lc[4];
  if (threadIdx.x < 4) lc[threadIdx.x] = 0;
  __syncthreads();
  int i = blockIdx.x * 256 + threadIdx.x;
  atomicAdd(&lc[t[i]], 1);
  __syncthreads();
  if (threadIdx.x < 4) atomicAdd(&cnt[threadIdx.x], lc[threadIdx.x]);
}

// ---- fused triangular GEMM-reduce: one 128x128 tile per block,
//      K-chunked double-buffered 2-phase pipeline ----
__global__ __launch_bounds__(256, 2) void k_main(const unsigned short* __restrict__ xn,
                                                 const int* __restrict__ tgt,
                                                 const int* __restrict__ cnt,
                                                 float* __restrict__ out) {
  __shared__ char  lds[2][2][128 * BKB];   // [buf][A|B][128 rows x 128B] = 64 KB
  __shared__ int   ltrow[128], ltcol[128];
  __shared__ float lW[16];
  __shared__ int   lsL;
  __shared__ float wred[4];

  // block -> (r, cb) upper-triangular-inclusive pair
  int bid = blockIdx.x;
  int r = 0, rem = bid;
  while (rem >= NB - r) { rem -= NB - r; ++r; }
  int cb = r + rem;

  const int tid = threadIdx.x;
  const int wave = tid >> 6, lane = tid & 63;

  const char* xb   = (const char*)xn;
  const char* srcA = xb + (size_t)r  * 128 * 512;
  const char* srcB = xb + (size_t)cb * 128 * 512;

  // ---- staging: one K-chunk (128 rows x 128B for A and B) ----
  // LDS dest linear: base(i,wave) + lane*16 ; global src pre-swizzled (row&7)<<4
  auto stage = [&](int buf, int chunk) {
    int inner = (lane & 7) * 16;
#pragma unroll
    for (int i = 0; i < 4; ++i) {
      int rbase = i * 32 + wave * 8;            // wave-uniform
      int row   = rbase + (lane >> 3);
      int sw    = (row & 7) << 4;
      size_t go = (size_t)row * 512 + chunk * BKB + (inner ^ sw);
      gl_lds16(srcA + go, &lds[buf][0][rbase * BKB]);
      gl_lds16(srcB + go, &lds[buf][1][rbase * BKB]);
    }
  };

  stage(0, 0);   // prologue: chunk 0 into buf 0

  if (tid < 128) { ltrow[tid] = tgt[r * 128 + tid]; ltcol[tid] = tgt[cb * 128 + tid]; }
  if (tid < 16) {
    int ta = tid >> 2, tb = tid & 3;
    float w = 0.0f;
#pragma unroll
    for (int i = 0; i < 4; ++i) {
      int ci = cnt[i];
      if (ci > 0 && ((ta == i) == (tb == i))) w += 1.0f / (float)ci;
    }
    lW[tid] = w;
  }
  if (tid == 0) {
    int L = -1;
    for (int i = 0; i < 4; ++i) if (cnt[i] > 0) L = i;
    lsL = L;
  }
  __syncthreads();   // drains prologue stage (vmcnt 0) + setup

  // 2x2 waves of 64x64; 4x4 frags of 16x16x32 per wave
  const int wr = (wave >> 1) * 64, wc = (wave & 1) * 64;
  f32x4 acc[4][4];
#pragma unroll
  for (int m = 0; m < 4; ++m)
#pragma unroll
    for (int n = 0; n < 4; ++n)
      acc[m][n] = (f32x4){0.f, 0.f, 0.f, 0.f};

  const int l15 = lane & 15;
  const int kb_lane = (lane >> 4) << 4;   // 0,16,32,48 byte k-offset within 64B k-block

  int cur = 0;
  for (int c = 0; c < NCHUNK; ++c) {
    if (c + 1 < NCHUNK) stage(cur ^ 1, c + 1);   // issue next-chunk loads first

    const char* cA = lds[cur][0];
    const char* cB = lds[cur][1];
#pragma unroll
    for (int kblk = 0; kblk < 2; ++kblk) {
      bf16x8 af[4], bfr[4];
      int kb = kblk * 64 + kb_lane;
#pragma unroll
      for (int m = 0; m < 4; ++m) {
        int arow = wr + m * 16 + l15;
        af[m] = *reinterpret_cast<const bf16x8*>(cA + arow * BKB + (kb ^ ((arow & 7) << 4)));
      }
#pragma unroll
      for (int n = 0; n < 4; ++n) {
        int brow = wc + n * 16 + l15;
        bfr[n] = *reinterpret_cast<const bf16x8*>(cB + brow * BKB + (kb ^ ((brow & 7) << 4)));
      }
#pragma unroll
      for (int m = 0; m < 4; ++m)
#pragma unroll
        for (int n = 0; n < 4; ++n)
          acc[m][n] = __builtin_amdgcn_mfma_f32_16x16x32_bf16(af[m], bfr[n], acc[m][n], 0, 0, 0);
    }
    __syncthreads();   // drains next-chunk stage + protects buffer reuse
    cur ^= 1;
  }

  // epilogue: C/D layout col=lane&15, row=(lane>>4)*4+reg (m89-verified)
  const int L = lsL;
  float lsum = 0.0f;
  const int rowj = (lane >> 4) * 4;
#pragma unroll
  for (int m = 0; m < 4; ++m) {
#pragma unroll
    for (int n = 0; n < 4; ++n) {
#pragma unroll
      for (int j = 0; j < 4; ++j) {
        int ar = wr + m * 16 + rowj + j;
        int bc = wc + n * 16 + l15;
        int ga = r * 128 + ar, gb = cb * 128 + bc;
        if (ga < gb) {
          float cv = acc[m][n][j];
          int ta = ltrow[ar], tb = ltcol[bc];
          float contrib = lW[ta * 4 + tb] * (1.0f - cv);
          if ((ta == L) != (tb == L)) contrib += fmaxf(cv - 0.5f, 0.0f);
          lsum += contrib;
        }
      }
    }
  }
#pragma unroll
  for (int off = 32; off; off >>= 1) lsum += __shfl_xor(lsum, off);
  if (lane == 0) wred[wave] = lsum;
  __syncthreads();
  if (tid == 0) atomicAdd(out, (wred[0] + wred[1] + wred[2] + wred[3]) * (1.0f / 8192.0f));
}

extern "C" void kernel_launch(void* const* d_in, const int* in_sizes, int n_in,
                              void* d_out, int out_size, void* d_ws, size_t ws_size,
                              hipStream_t stream) {
  (void)in_sizes; (void)n_in; (void)out_size; (void)ws_size;
  const float* x  = (const float*)d_in[0];
  const int* tgt  = (const int*)d_in[1];
  float* out      = (float*)d_out;
  int* cnt        = (int*)d_ws;
  unsigned short* xn = (unsigned short*)((char*)d_ws + XN_OFF);

  hipMemsetAsync(d_out, 0, sizeof(float), stream);
  hipMemsetAsync(cnt, 0, 4 * sizeof(int), stream);
  k_norm<<<NROWS / 4, 256, 0, stream>>>(x, xn);
  k_hist<<<NROWS / 256, 256, 0, stream>>>(tgt, cnt);
  k_main<<<NB * (NB + 1) / 2, 256, 0, stream>>>(xn, tgt, cnt, out);
}

// Round 3
// 59.316 us; speedup vs baseline: 1.9423x; 1.4034x over previous
//
#include <hip/hip_runtime.h>

#define NROWS 8192
#define EDIM  256
#define NB    64               // 8192 / 128 row-blocks
#define NPAIR 2080             // NB*(NB+1)/2
#define BKB   64               // bytes per K-chunk row (32 bf16 elems = one MFMA k-step)
#define NCHUNK 8               // 512 B/row / 64 B
// ws layout: cnt[4] @0, partial[NPAIR] @256, xn @16384
#define PART_OFF 256
#define XN_OFF   16384

typedef __bf16 bf16x8 __attribute__((ext_vector_type(8)));
typedef float  f32x4  __attribute__((ext_vector_type(4)));

__device__ __forceinline__ unsigned short f2bf(float f) {
  unsigned int u = __float_as_uint(f);
  u += 0x7fffu + ((u >> 16) & 1u);      // round-to-nearest-even
  return (unsigned short)(u >> 16);
}

__device__ __forceinline__ void gl_lds16(const void* g, void* l) {
  __builtin_amdgcn_global_load_lds(
      (const __attribute__((address_space(1))) unsigned int*)g,
      (__attribute__((address_space(3))) unsigned int*)l, 16, 0, 0);
}

// ---- row normalize + bf16 convert: 1 wave per row ----
__global__ __launch_bounds__(256) void k_norm(const float* __restrict__ x,
                                              unsigned short* __restrict__ xn) {
  int row  = blockIdx.x * 4 + (threadIdx.x >> 6);
  int lane = threadIdx.x & 63;
  float4 v = reinterpret_cast<const float4*>(x)[row * 64 + lane];
  float ss = v.x * v.x + v.y * v.y + v.z * v.z + v.w * v.w;
#pragma unroll
  for (int off = 32; off; off >>= 1) ss += __shfl_xor(ss, off);
  float inv = 1.0f / fmaxf(sqrtf(ss), 1e-8f);
  ushort4 o;
  o.x = f2bf(v.x * inv); o.y = f2bf(v.y * inv);
  o.z = f2bf(v.z * inv); o.w = f2bf(v.w * inv);
  reinterpret_cast<ushort4*>(xn)[row * 64 + lane] = o;
}

// ---- class histogram ----
__global__ __launch_bounds__(256) void k_hist(const int* __restrict__ t,
                                              int* __restrict__ cnt) {
  __shared__ int lc[4];
  if (threadIdx.x < 4) lc[threadIdx.x] = 0;
  __syncthreads();
  int i = blockIdx.x * 256 + threadIdx.x;
  atomicAdd(&lc[t[i]], 1);
  __syncthreads();
  if (threadIdx.x < 4) atomicAdd(&cnt[threadIdx.x], lc[threadIdx.x]);
}

// ---- fused triangular GEMM-reduce: one 128x128 tile per block ----
// BKB=64 double-buffered -> 34 KB LDS -> 4 blocks/CU
__global__ __launch_bounds__(256, 4) void k_main(const unsigned short* __restrict__ xn,
                                                 const int* __restrict__ tgt,
                                                 const int* __restrict__ cnt,
                                                 float* __restrict__ partial) {
  __shared__ char  lds[2][2][128 * BKB];   // [buf][A|B][128 rows x 64B] = 32 KB
  __shared__ int   ltrow[128], ltcol[128];
  __shared__ float lW[16];
  __shared__ int   lsL;
  __shared__ float wred[4];

  // XCD-aware bijective swizzle: 2080 = 8 * 260
  int bid0 = blockIdx.x;
  int bid  = (bid0 & 7) * (NPAIR / 8) + (bid0 >> 3);

  // bid -> (r, cb) upper-triangular-inclusive pair
  int r = 0, rem = bid;
  while (rem >= NB - r) { rem -= NB - r; ++r; }
  int cb = r + rem;

  const int tid = threadIdx.x;
  const int wave = tid >> 6, lane = tid & 63;

  const char* xb   = (const char*)xn;
  const char* srcA = xb + (size_t)r  * 128 * 512;
  const char* srcB = xb + (size_t)cb * 128 * 512;

  // stage one K-chunk (128 rows x 64B, A and B); linear LDS dest,
  // swizzle key ((row>>1)&3)<<4 applied on the global source (rule #21)
  auto stage = [&](int buf, int chunk) {
    int slot16 = (lane & 3) * 16;
#pragma unroll
    for (int i = 0; i < 2; ++i) {
      int rbase = i * 64 + wave * 16;          // wave-uniform
      int row   = rbase + (lane >> 2);
      int key   = ((row >> 1) & 3) << 4;
      size_t go = (size_t)row * 512 + chunk * BKB + (slot16 ^ key);
      gl_lds16(srcA + go, &lds[buf][0][rbase * BKB]);
      gl_lds16(srcB + go, &lds[buf][1][rbase * BKB]);
    }
  };

  stage(0, 0);   // prologue

  if (tid < 128) { ltrow[tid] = tgt[r * 128 + tid]; ltcol[tid] = tgt[cb * 128 + tid]; }
  if (tid < 16) {
    int ta = tid >> 2, tb = tid & 3;
    float w = 0.0f;
#pragma unroll
    for (int i = 0; i < 4; ++i) {
      int ci = cnt[i];
      if (ci > 0 && ((ta == i) == (tb == i))) w += 1.0f / (float)ci;
    }
    lW[tid] = w;
  }
  if (tid == 0) {
    int L = -1;
    for (int i = 0; i < 4; ++i) if (cnt[i] > 0) L = i;
    lsL = L;
  }
  __syncthreads();

  // 2x2 waves of 64x64; 4x4 frags of 16x16x32; one MFMA k-step per chunk
  const int wr = (wave >> 1) * 64, wc = (wave & 1) * 64;
  f32x4 acc[4][4];
#pragma unroll
  for (int m = 0; m < 4; ++m)
#pragma unroll
    for (int n = 0; n < 4; ++n)
      acc[m][n] = (f32x4){0.f, 0.f, 0.f, 0.f};

  const int l15 = lane & 15;
  const int kb_lane = (lane >> 4) << 4;   // 0,16,32,48 byte k-offset within 64B row

  int cur = 0;
  for (int c = 0; c < NCHUNK; ++c) {
    if (c + 1 < NCHUNK) stage(cur ^ 1, c + 1);   // issue next-chunk loads first

    const char* cA = lds[cur][0];
    const char* cB = lds[cur][1];
    bf16x8 af[4], bfr[4];
#pragma unroll
    for (int m = 0; m < 4; ++m) {
      int arow = wr + m * 16 + l15;
      af[m] = *reinterpret_cast<const bf16x8*>(cA + arow * BKB + (kb_lane ^ (((arow >> 1) & 3) << 4)));
    }
#pragma unroll
    for (int n = 0; n < 4; ++n) {
      int brow = wc + n * 16 + l15;
      bfr[n] = *reinterpret_cast<const bf16x8*>(cB + brow * BKB + (kb_lane ^ (((brow >> 1) & 3) << 4)));
    }
#pragma unroll
    for (int m = 0; m < 4; ++m)
#pragma unroll
      for (int n = 0; n < 4; ++n)
        acc[m][n] = __builtin_amdgcn_mfma_f32_16x16x32_bf16(af[m], bfr[n], acc[m][n], 0, 0, 0);

    __syncthreads();   // protects buffer reuse + drains next-chunk stage
    cur ^= 1;
  }

  // epilogue: C/D layout col=lane&15, row=(lane>>4)*4+reg (m89-verified)
  const int L = lsL;
  float lsum = 0.0f;
  const int rowj = (lane >> 4) * 4;
#pragma unroll
  for (int m = 0; m < 4; ++m) {
#pragma unroll
    for (int n = 0; n < 4; ++n) {
#pragma unroll
      for (int j = 0; j < 4; ++j) {
        int ar = wr + m * 16 + rowj + j;
        int bc = wc + n * 16 + l15;
        int ga = r * 128 + ar, gb = cb * 128 + bc;
        if (ga < gb) {
          float cv = acc[m][n][j];
          int ta = ltrow[ar], tb = ltcol[bc];
          float contrib = lW[ta * 4 + tb] * (1.0f - cv);
          if ((ta == L) != (tb == L)) contrib += fmaxf(cv - 0.5f, 0.0f);
          lsum += contrib;
        }
      }
    }
  }
#pragma unroll
  for (int off = 32; off; off >>= 1) lsum += __shfl_xor(lsum, off);
  if (lane == 0) wred[wave] = lsum;
  __syncthreads();
  if (tid == 0) partial[bid] = wred[0] + wred[1] + wred[2] + wred[3];
}

// ---- final reduce: 2080 partials -> scalar ----
__global__ __launch_bounds__(256) void k_reduce(const float* __restrict__ partial,
                                                float* __restrict__ out) {
  __shared__ float red[4];
  int tid = threadIdx.x, wave = tid >> 6, lane = tid & 63;
  float s = 0.0f;
  for (int i = tid; i < NPAIR; i += 256) s += partial[i];
#pragma unroll
  for (int off = 32; off; off >>= 1) s += __shfl_xor(s, off);
  if (lane == 0) red[wave] = s;
  __syncthreads();
  if (tid == 0) out[0] = (red[0] + red[1] + red[2] + red[3]) * (1.0f / 8192.0f);
}

extern "C" void kernel_launch(void* const* d_in, const int* in_sizes, int n_in,
                              void* d_out, int out_size, void* d_ws, size_t ws_size,
                              hipStream_t stream) {
  (void)in_sizes; (void)n_in; (void)out_size; (void)ws_size;
  const float* x  = (const float*)d_in[0];
  const int* tgt  = (const int*)d_in[1];
  float* out      = (float*)d_out;
  int* cnt        = (int*)d_ws;
  float* partial  = (float*)((char*)d_ws + PART_OFF);
  unsigned short* xn = (unsigned short*)((char*)d_ws + XN_OFF);

  hipMemsetAsync(cnt, 0, 4 * sizeof(int), stream);
  k_norm<<<NROWS / 4, 256, 0, stream>>>(x, xn);
  k_hist<<<NROWS / 256, 256, 0, stream>>>(tgt, cnt);
  k_main<<<NPAIR, 256, 0, stream>>>(xn, tgt, cnt, partial);
  k_reduce<<<1, 256, 0, stream>>>(partial, out);
}